// Round 4
// baseline (306.260 us; speedup 1.0000x reference)
//
#include <hip/hip_runtime.h>
#include <hip/hip_bf16.h>

// Problem constants
#define NB   32
#define CCH  128
#define HH   64
#define WW   64
#define DBOT 512
#define EPS_LN 1e-5f

typedef __attribute__((ext_vector_type(8))) short bf16x8;
typedef __attribute__((ext_vector_type(4))) float f32x4;

__device__ __forceinline__ float bf2f(unsigned short u) {
    return __uint_as_float(((unsigned)u) << 16);
}
__device__ __forceinline__ unsigned short f2bf(float f) {
    __hip_bfloat16 h = __float2bfloat16(f);
    return *(unsigned short*)&h;
}

// ---------------------------------------------------------------------------
// K0: convert pointwise weights fp32 -> bf16 into workspace
// ---------------------------------------------------------------------------
__global__ __launch_bounds__(256) void wcvt_kernel(
    const float* __restrict__ w1, const float* __restrict__ w2,
    __hip_bfloat16* __restrict__ o1, __hip_bfloat16* __restrict__ o2)
{
    int i = blockIdx.x * 256 + threadIdx.x;   // 0 .. 65535
    o1[i] = __float2bfloat16(w1[i]);
    o2[i] = __float2bfloat16(w2[i]);
}

// ---------------------------------------------------------------------------
// K1: depthwise 7x7 conv + bias -> conv_out ([n][h][c][w], bf16)
// one block per (n, c) plane. Padded-row LDS: 3 zero rows top/bottom ->
// branch-free inner loop. __launch_bounds__(256,4): allow 128 VGPR, no spill.
// ---------------------------------------------------------------------------
#define XS 76   // LDS row stride (floats): 4 left pad + 64 data + 8 right pad

__global__ __launch_bounds__(256, 4) void dwconv_kernel(
    const float* __restrict__ x, const float* __restrict__ dw_w,
    const float* __restrict__ dw_b, unsigned short* __restrict__ cout)
{
    __shared__ float xs[70 * XS];   // rows 0-2 pad, 3-66 data, 67-69 pad

    const int t = threadIdx.x;
    const int n = blockIdx.x >> 7;
    const int c = blockIdx.x & 127;

    const float* xp = x + ((size_t)(n * CCH + c) << 12);

    // stage plane (data row r -> LDS row r+3)
    #pragma unroll
    for (int i = 0; i < 4; ++i) {
        int idx = i * 256 + t;          // float4 index 0..1023
        int r   = idx >> 4;
        int c4  = idx & 15;
        float4 v = ((const float4*)xp)[idx];
        *(float4*)&xs[(r + 3) * XS + 4 + c4 * 4] = v;
    }
    // side pads of data rows: 64 rows x 12 floats
    #pragma unroll
    for (int i = 0; i < 3; ++i) {
        int idx = i * 256 + t;          // 0..767
        int r   = idx / 12;
        int p   = idx % 12;
        int col = (p < 4) ? p : (p + 64);
        xs[(r + 3) * XS + col] = 0.0f;
    }
    // top/bottom pad rows: 6 x 76 = 456 floats
    #pragma unroll
    for (int i = 0; i < 2; ++i) {
        int idx = i * 256 + t;
        if (idx < 456) {
            int rr = idx / 76, cc = idx % 76;
            int lr = (rr < 3) ? rr : (rr + 64);   // 0,1,2,67,68,69
            xs[lr * XS + cc] = 0.0f;
        }
    }

    // weights: wave-uniform -> SGPRs
    float wgt[49];
    const float* wp = dw_w + c * 49;
    #pragma unroll
    for (int j = 0; j < 49; ++j) wgt[j] = wp[j];
    const float bias = dw_b[c];

    __syncthreads();

    const int h  = t >> 2;
    const int w0 = (t & 3) << 4;

    float acc[16];
    #pragma unroll
    for (int j = 0; j < 16; ++j) acc[j] = bias;

    #pragma unroll
    for (int kh = 0; kh < 7; ++kh) {
        float r[24];
        const float* row = &xs[(h + kh) * XS + w0];   // branch-free, padded
        #pragma unroll
        for (int j = 0; j < 6; ++j) *(float4*)&r[j * 4] = *(const float4*)&row[j * 4];
        #pragma unroll
        for (int kw = 0; kw < 7; ++kw)
            #pragma unroll
            for (int j = 0; j < 16; ++j)
                acc[j] = fmaf(r[j + kw + 1], wgt[kh * 7 + kw], acc[j]);
    }

    // pack 16 bf16 into two uint4 (packed cvt, SROA-safe)
    uint4 s0, s1;
    {
        __hip_bfloat162 p0 = __float22bfloat162_rn(make_float2(acc[0],  acc[1]));
        __hip_bfloat162 p1 = __float22bfloat162_rn(make_float2(acc[2],  acc[3]));
        __hip_bfloat162 p2 = __float22bfloat162_rn(make_float2(acc[4],  acc[5]));
        __hip_bfloat162 p3 = __float22bfloat162_rn(make_float2(acc[6],  acc[7]));
        __hip_bfloat162 p4 = __float22bfloat162_rn(make_float2(acc[8],  acc[9]));
        __hip_bfloat162 p5 = __float22bfloat162_rn(make_float2(acc[10], acc[11]));
        __hip_bfloat162 p6 = __float22bfloat162_rn(make_float2(acc[12], acc[13]));
        __hip_bfloat162 p7 = __float22bfloat162_rn(make_float2(acc[14], acc[15]));
        s0.x = *(unsigned*)&p0; s0.y = *(unsigned*)&p1;
        s0.z = *(unsigned*)&p2; s0.w = *(unsigned*)&p3;
        s1.x = *(unsigned*)&p4; s1.y = *(unsigned*)&p5;
        s1.z = *(unsigned*)&p6; s1.w = *(unsigned*)&p7;
    }
    unsigned short* op = cout + ((size_t)((n * 64 + h) * 128 + c) << 6) + w0;
    *(uint4*)op       = s0;
    *(uint4*)(op + 8) = s1;
}

// ---------------------------------------------------------------------------
// K2: LayerNorm + pointwise MLP (bf16 MFMA) + bias + residual, NCHW fp32 out
// 512-thread block = TWO (n,h) rows (waves 0-3 row 0, waves 4-7 row 1).
// __launch_bounds__(512,4): <=128 VGPR so af/oacc/hacc never spill.
// dc-loop fully unrolled so next chunk's weight loads hoist across barriers.
// ---------------------------------------------------------------------------
#define HS 136   // sH row stride in shorts (272 B = 17 x 16 B)

__global__ __launch_bounds__(512, 4) void mlp_kernel(
    const unsigned short* __restrict__ conv,  // [n][h][c][w] bf16
    const float* __restrict__ gamma,          // 128
    const float* __restrict__ beta,           // 128
    const __hip_bfloat16* __restrict__ w1,    // 512 x 128 (bf16)
    const float* __restrict__ b1,             // 512
    const __hip_bfloat16* __restrict__ w2,    // 128 x 512 (bf16)
    const float* __restrict__ b2,             // 128
    const float* __restrict__ x,              // NCHW fp32
    float* __restrict__ out)                  // NCHW fp32
{
    __shared__ union {
        unsigned short xs[2][CCH * 64];   // staged [row][c][w] (32 KB)
        unsigned short h[2][64 * HS];     // H chunk [row][pos][d] (34.8 KB)
    } u;
    __shared__ float sPart[2][2][256];
    __shared__ float sMu[2][64], sRstd[2][64];

    const int t     = threadIdx.x;
    const int rowId = t >> 8;            // 0/1: which (n,h) row
    const int tr    = t & 255;
    const int wave  = tr >> 6;           // 0..3 within row
    const int lane  = t & 63;
    const int q     = lane >> 4;         // 0..3
    const int ln    = lane & 15;         // 0..15
    const int wm    = (wave >> 1) * 32;  // wave M offset (0/32)
    const int wn    = (wave & 1) * 64;   // wave N offset (0/64)

    const int grow = blockIdx.x * 2 + rowId;
    const int n = grow >> 6;
    const int h = grow & 63;

    // ---- stage this row's plane [c][w] (16 KB) into LDS ----
    {
        const uint4* src = (const uint4*)(conv + ((size_t)grow << 13));
        #pragma unroll
        for (int i = 0; i < 4; ++i) {
            int idx = i * 256 + tr;
            *(uint4*)&u.xs[rowId][idx * 8] = src[idx];
        }
    }
    __syncthreads();

    // ---- LN stats ----
    {
        const int wI = tr & 63, cg = tr >> 6;
        float s = 0.f, s2 = 0.f;
        #pragma unroll
        for (int j = 0; j < 32; ++j) {
            float v = bf2f(u.xs[rowId][(cg * 32 + j) * 64 + wI]);
            s += v;
            s2 = fmaf(v, v, s2);
        }
        sPart[rowId][0][cg * 64 + wI] = s;
        sPart[rowId][1][cg * 64 + wI] = s2;
    }
    __syncthreads();
    if (tr < 64) {
        float su = 0.f, sq = 0.f;
        #pragma unroll
        for (int g = 0; g < 4; ++g) {
            su += sPart[rowId][0][g * 64 + tr];
            sq += sPart[rowId][1][g * 64 + tr];
        }
        float mu  = su * (1.0f / 128.0f);
        float var = sq * (1.0f / 128.0f) - mu * mu;
        sMu[rowId][tr]   = mu;
        sRstd[rowId][tr] = 1.0f / sqrtf(var + EPS_LN);
    }
    __syncthreads();

    // ---- build normalized A-fragments in registers: A[m=pos][k=c] ----
    bf16x8 af[2][4];
    #pragma unroll
    for (int mt = 0; mt < 2; ++mt) {
        const int pos = wm + mt * 16 + ln;
        const float mu = sMu[rowId][pos], rs = sRstd[rowId][pos];
        #pragma unroll
        for (int kb = 0; kb < 4; ++kb) {
            const int c0 = kb * 32 + q * 8;
            float4 g0  = *(const float4*)(gamma + c0);
            float4 g1  = *(const float4*)(gamma + c0 + 4);
            float4 be0 = *(const float4*)(beta + c0);
            float4 be1 = *(const float4*)(beta + c0 + 4);
            float gv[8] = {g0.x, g0.y, g0.z, g0.w, g1.x, g1.y, g1.z, g1.w};
            float bv[8] = {be0.x, be0.y, be0.z, be0.w, be1.x, be1.y, be1.z, be1.w};
            bf16x8 a;
            #pragma unroll
            for (int jp = 0; jp < 4; ++jp) {
                float v0 = bf2f(u.xs[rowId][(c0 + 2 * jp)     * 64 + pos]);
                float v1 = bf2f(u.xs[rowId][(c0 + 2 * jp + 1) * 64 + pos]);
                float r0 = (v0 - mu) * rs * gv[2 * jp]     + bv[2 * jp];
                float r1 = (v1 - mu) * rs * gv[2 * jp + 1] + bv[2 * jp + 1];
                __hip_bfloat162 p = __float22bfloat162_rn(make_float2(r0, r1));
                unsigned pu = *(unsigned*)&p;
                a[2 * jp]     = (short)(pu & 0xffff);
                a[2 * jp + 1] = (short)(pu >> 16);
            }
            af[mt][kb] = a;
        }
    }

    f32x4 oacc[2][4];
    #pragma unroll
    for (int mt = 0; mt < 2; ++mt)
        #pragma unroll
        for (int ct = 0; ct < 4; ++ct) oacc[mt][ct] = (f32x4){0.f, 0.f, 0.f, 0.f};

    #pragma unroll
    for (int dc = 0; dc < 4; ++dc) {
        const int d0 = dc * 128;

        // stage 1: Hc = Y @ W1^T (A from regs, B from global/L2)
        f32x4 hacc[2][4];
        #pragma unroll
        for (int mt = 0; mt < 2; ++mt)
            #pragma unroll
            for (int dt = 0; dt < 4; ++dt) hacc[mt][dt] = (f32x4){0.f, 0.f, 0.f, 0.f};

        #pragma unroll
        for (int kb = 0; kb < 4; ++kb) {
            bf16x8 bw[4];
            #pragma unroll
            for (int dt = 0; dt < 4; ++dt) {
                int d = d0 + wn + dt * 16 + ln;
                bw[dt] = *(const bf16x8*)(w1 + (size_t)d * 128 + kb * 32 + q * 8);
            }
            #pragma unroll
            for (int mt = 0; mt < 2; ++mt)
                #pragma unroll
                for (int dt = 0; dt < 4; ++dt)
                    hacc[mt][dt] = __builtin_amdgcn_mfma_f32_16x16x32_bf16(
                        af[mt][kb], bw[dt], hacc[mt][dt], 0, 0, 0);
        }

        __syncthreads();   // prev readers of u done

        // bias + relu + bf16 -> sH (packed cvt)
        #pragma unroll
        for (int dt = 0; dt < 4; ++dt) {
            const int dl = wn + dt * 16 + ln;
            const float b1v = b1[d0 + dl];
            #pragma unroll
            for (int mt = 0; mt < 2; ++mt) {
                float v0 = fmaxf(hacc[mt][dt][0] + b1v, 0.0f);
                float v1 = fmaxf(hacc[mt][dt][1] + b1v, 0.0f);
                float v2 = fmaxf(hacc[mt][dt][2] + b1v, 0.0f);
                float v3 = fmaxf(hacc[mt][dt][3] + b1v, 0.0f);
                __hip_bfloat162 pa = __float22bfloat162_rn(make_float2(v0, v1));
                __hip_bfloat162 pb = __float22bfloat162_rn(make_float2(v2, v3));
                unsigned ua = *(unsigned*)&pa, ub = *(unsigned*)&pb;
                const int rbase = (wm + mt * 16 + q * 4) * HS + dl;
                u.h[rowId][rbase]          = (unsigned short)(ua & 0xffff);
                u.h[rowId][rbase + HS]     = (unsigned short)(ua >> 16);
                u.h[rowId][rbase + 2 * HS] = (unsigned short)(ub & 0xffff);
                u.h[rowId][rbase + 3 * HS] = (unsigned short)(ub >> 16);
            }
        }
        __syncthreads();

        // stage 2: O += H @ W2_chunk^T
        #pragma unroll
        for (int kb = 0; kb < 4; ++kb) {
            bf16x8 ah[2];
            #pragma unroll
            for (int mt = 0; mt < 2; ++mt)
                ah[mt] = *(const bf16x8*)&u.h[rowId][(wm + mt * 16 + ln) * HS + kb * 32 + q * 8];
            bf16x8 bw2[4];
            #pragma unroll
            for (int ct = 0; ct < 4; ++ct) {
                int c = wn + ct * 16 + ln;
                bw2[ct] = *(const bf16x8*)(w2 + (size_t)c * DBOT + d0 + kb * 32 + q * 8);
            }
            #pragma unroll
            for (int mt = 0; mt < 2; ++mt)
                #pragma unroll
                for (int ct = 0; ct < 4; ++ct)
                    oacc[mt][ct] = __builtin_amdgcn_mfma_f32_16x16x32_bf16(
                        ah[mt], bw2[ct], oacc[mt][ct], 0, 0, 0);
        }
    }

    // ---- epilogue: direct float4 stores, out = O + b2 + x (NCHW) ----
    #pragma unroll
    for (int ct = 0; ct < 4; ++ct) {
        const int c = wn + ct * 16 + ln;
        const float b2v = b2[c];
        #pragma unroll
        for (int mt = 0; mt < 2; ++mt) {
            size_t base = ((size_t)(n * CCH + c) << 12) + (h << 6) + wm + mt * 16 + q * 4;
            float4 xr = *(const float4*)(x + base);
            float4 o;
            o.x = oacc[mt][ct][0] + b2v + xr.x;
            o.y = oacc[mt][ct][1] + b2v + xr.y;
            o.z = oacc[mt][ct][2] + b2v + xr.z;
            o.w = oacc[mt][ct][3] + b2v + xr.w;
            *(float4*)(out + base) = o;
        }
    }
}

// ---------------------------------------------------------------------------
extern "C" void kernel_launch(void* const* d_in, const int* in_sizes, int n_in,
                              void* d_out, int out_size, void* d_ws, size_t ws_size,
                              hipStream_t stream)
{
    const float* x     = (const float*)d_in[0];
    const float* dw_w  = (const float*)d_in[1];
    const float* dw_b  = (const float*)d_in[2];
    const float* gamma = (const float*)d_in[3];
    const float* beta  = (const float*)d_in[4];
    const float* pw1_w = (const float*)d_in[5];
    const float* pw1_b = (const float*)d_in[6];
    const float* pw2_w = (const float*)d_in[7];
    const float* pw2_b = (const float*)d_in[8];
    float* out = (float*)d_out;

    char* ws = (char*)d_ws;
    unsigned short* convb = (unsigned short*)ws;                       // 32 MiB
    __hip_bfloat16* w1b   = (__hip_bfloat16*)(ws + (size_t)33554432);  // 128 KiB
    __hip_bfloat16* w2b   = (__hip_bfloat16*)(ws + (size_t)33554432 + 131072);

    wcvt_kernel<<<256, 256, 0, stream>>>(pw1_w, pw2_w, w1b, w2b);
    dwconv_kernel<<<NB * CCH, 256, 0, stream>>>(x, dw_w, dw_b, convb);
    mlp_kernel<<<NB * HH / 2, 512, 0, stream>>>(convb, gamma, beta, w1b, pw1_b, w2b, pw2_b, x, out);
}